// Round 1
// baseline (278.023 us; speedup 1.0000x reference)
//
#include <hip/hip_runtime.h>

typedef int v4i __attribute__((ext_vector_type(4)));

#define KDIM 2048
#define NDIM 2048
#define BM 128
#define BN 128
#define BK 64

#define GLOAD_LDS16(g, l) __builtin_amdgcn_global_load_lds(                      \
    (const __attribute__((address_space(1))) void*)(g),                          \
    (__attribute__((address_space(3))) void*)(l), 16, 0, 0)

__device__ __forceinline__ int pack4q(float4 v, float s) {
  int a = __float2int_rn(v.x * s);
  int b = __float2int_rn(v.y * s);
  int c = __float2int_rn(v.z * s);
  int d = __float2int_rn(v.w * s);
  a = max(-128, min(127, a)); b = max(-128, min(127, b));
  c = max(-128, min(127, c)); d = max(-128, min(127, d));
  return (a & 0xff) | ((b & 0xff) << 8) | ((c & 0xff) << 16) | ((d & 0xff) << 24);
}

// One block (256 threads) per row of 2048 floats: absmax -> scale -> int8 quant.
__global__ __launch_bounds__(256) void quant_rows(const float* __restrict__ x,
                                                  signed char* __restrict__ q,
                                                  float* __restrict__ rscale) {
  const int row = blockIdx.x;
  const float4* xr = (const float4*)(x + (size_t)row * KDIM);
  float4 v0 = xr[threadIdx.x];
  float4 v1 = xr[256 + threadIdx.x];
  float m = fmaxf(fmaxf(fabsf(v0.x), fabsf(v0.y)), fmaxf(fabsf(v0.z), fabsf(v0.w)));
  m = fmaxf(m, fmaxf(fmaxf(fabsf(v1.x), fabsf(v1.y)), fmaxf(fabsf(v1.z), fabsf(v1.w))));
  #pragma unroll
  for (int off = 32; off > 0; off >>= 1) m = fmaxf(m, __shfl_xor(m, off));
  __shared__ float red[4];
  if ((threadIdx.x & 63) == 0) red[threadIdx.x >> 6] = m;
  __syncthreads();
  float xmax = fmaxf(fmaxf(red[0], red[1]), fmaxf(red[2], red[3]));
  xmax = fmaxf(xmax, 1e-5f);
  const float scale = 127.0f / xmax;
  int* qr = (int*)(q + (size_t)row * KDIM);
  qr[threadIdx.x] = pack4q(v0, scale);
  qr[256 + threadIdx.x] = pack4q(v1, scale);
  if (threadIdx.x == 0) rscale[row] = xmax * (1.0f / 127.0f);
}

// W (float {-1,0,1}) -> int8
__global__ __launch_bounds__(256) void quant_w(const float* __restrict__ W,
                                               signed char* __restrict__ Wq) {
  const int i = blockIdx.x * 256 + threadIdx.x;
  float4 v = ((const float4*)W)[i];
  int a = (int)v.x, b = (int)v.y, c = (int)v.z, d = (int)v.w;
  ((int*)Wq)[i] = (a & 0xff) | ((b & 0xff) << 8) | ((c & 0xff) << 16) | ((d & 0xff) << 24);
}

// C[m][n] = (sum_k A[m][k]*B[n][k]) * rscale[m]
// A: [M][K] int8 row-major, B: [N][K] int8 row-major (i.e. W itself).
// 128x128 tile, 4 waves in 2x2, each wave 64x64 via 4x4 frags of 16x16x64 i8 MFMA.
__global__ __launch_bounds__(256) void gemm_i8(const signed char* __restrict__ A,
                                               const signed char* __restrict__ B,
                                               const float* __restrict__ rscale,
                                               float* __restrict__ C) {
  __shared__ signed char lA[BM * BK];  // 8 KB
  __shared__ signed char lB[BN * BK];  // 8 KB
  const int bn = blockIdx.x & (NDIM / BN - 1);  // 16 column tiles
  const int bm = blockIdx.x >> 4;
  const int tid = threadIdx.x;
  const int wid = tid >> 6;
  const int lane = tid & 63;
  const int wr = wid >> 1, wc = wid & 1;

  v4i acc[4][4] = {};

  // Staging: per wave, 2 issues for A and 2 for B; each issue = 64 lanes x 16B = 16 rows.
  // LDS layout is linear [row][k] (64 B rows); dest = wave-uniform base + lane*16 (HW).
  const signed char* pa = A + ((size_t)(bm * BM + wid * 32 + (lane >> 2))) * KDIM + (lane & 3) * 16;
  const signed char* pb = B + ((size_t)(bn * BN + wid * 32 + (lane >> 2))) * KDIM + (lane & 3) * 16;
  signed char* la0 = lA + wid * 2048;
  signed char* lb0 = lB + wid * 2048;

  const int ar = wr * 64 + (lane & 15);   // A frag row within tile (+m*16)
  const int br = wc * 64 + (lane & 15);   // B frag row within tile (+n*16)
  const int ko = (lane >> 4) * 16;        // k byte offset within BK

  for (int kt = 0; kt < KDIM / BK; ++kt) {
    const signed char* pak = pa + kt * BK;
    const signed char* pbk = pb + kt * BK;
    GLOAD_LDS16(pak, la0);
    GLOAD_LDS16(pak + 16 * KDIM, la0 + 1024);
    GLOAD_LDS16(pbk, lb0);
    GLOAD_LDS16(pbk + 16 * KDIM, lb0 + 1024);
    __syncthreads();  // compiler emits vmcnt(0) drain before barrier

    v4i af[4], bf[4];
    #pragma unroll
    for (int m = 0; m < 4; ++m)
      af[m] = *(const v4i*)(lA + (ar + m * 16) * BK + ko);
    #pragma unroll
    for (int n = 0; n < 4; ++n)
      bf[n] = *(const v4i*)(lB + (br + n * 16) * BK + ko);

    #pragma unroll
    for (int m = 0; m < 4; ++m)
      #pragma unroll
      for (int n = 0; n < 4; ++n)
        acc[m][n] = __builtin_amdgcn_mfma_i32_16x16x64_i8(af[m], bf[n], acc[m][n], 0, 0, 0);
    __syncthreads();
  }

  // Epilogue: C/D layout col = lane&15, row = (lane>>4)*4 + reg.
  const int col0 = bn * BN + wc * 64 + (lane & 15);
  const int rbase = bm * BM + wr * 64 + (lane >> 4) * 4;
  #pragma unroll
  for (int m = 0; m < 4; ++m) {
    #pragma unroll
    for (int r = 0; r < 4; ++r) {
      const int row = rbase + m * 16 + r;
      const float s = rscale[row];
      float* crow = C + (size_t)row * NDIM + col0;
      #pragma unroll
      for (int n = 0; n < 4; ++n) crow[n * 16] = (float)acc[m][n][r] * s;
    }
  }
}

extern "C" void kernel_launch(void* const* d_in, const int* in_sizes, int n_in,
                              void* d_out, int out_size, void* d_ws, size_t ws_size,
                              hipStream_t stream) {
  const float* x = (const float*)d_in[0];
  const float* W = (const float*)d_in[1];
  float* out = (float*)d_out;
  const int M = in_sizes[0] / KDIM;  // 4*8192 = 32768

  signed char* q = (signed char*)d_ws;                       // M*K   = 64 MB
  signed char* Wq = q + (size_t)M * KDIM;                    // N*K   =  4 MB
  float* rscale = (float*)(Wq + (size_t)NDIM * KDIM);        // M*4   = 128 KB

  quant_rows<<<M, 256, 0, stream>>>(x, q, rscale);
  quant_w<<<(NDIM * KDIM / 4) / 256, 256, 0, stream>>>(W, Wq);
  gemm_i8<<<(M / BM) * (NDIM / BN), 256, 0, stream>>>(q, Wq, rscale, out);
}

// Round 2
// 239.582 us; speedup vs baseline: 1.1605x; 1.1605x over previous
//
#include <hip/hip_runtime.h>

typedef int v4i __attribute__((ext_vector_type(4)));

#define KDIM 2048
#define NDIM 2048

#define GLOAD16(g, l) __builtin_amdgcn_global_load_lds(                      \
    (const __attribute__((address_space(1))) void*)(g),                      \
    (__attribute__((address_space(3))) void*)(l), 16, 0, 0)

// ---------------- quant kernels ----------------

__device__ __forceinline__ int pack4q(float4 v, float s) {
  int a = __float2int_rn(v.x * s);
  int b = __float2int_rn(v.y * s);
  int c = __float2int_rn(v.z * s);
  int d = __float2int_rn(v.w * s);
  a = max(-128, min(127, a)); b = max(-128, min(127, b));
  c = max(-128, min(127, c)); d = max(-128, min(127, d));
  return (a & 0xff) | ((b & 0xff) << 8) | ((c & 0xff) << 16) | ((d & 0xff) << 24);
}

__global__ __launch_bounds__(256) void quant_rows(const float* __restrict__ x,
                                                  signed char* __restrict__ q,
                                                  float* __restrict__ rscale) {
  const int row = blockIdx.x;
  const float4* xr = (const float4*)(x + (size_t)row * KDIM);
  float4 v0 = xr[threadIdx.x];
  float4 v1 = xr[256 + threadIdx.x];
  float m = fmaxf(fmaxf(fabsf(v0.x), fabsf(v0.y)), fmaxf(fabsf(v0.z), fabsf(v0.w)));
  m = fmaxf(m, fmaxf(fmaxf(fabsf(v1.x), fabsf(v1.y)), fmaxf(fabsf(v1.z), fabsf(v1.w))));
  #pragma unroll
  for (int off = 32; off > 0; off >>= 1) m = fmaxf(m, __shfl_xor(m, off));
  __shared__ float red[4];
  if ((threadIdx.x & 63) == 0) red[threadIdx.x >> 6] = m;
  __syncthreads();
  float xmax = fmaxf(fmaxf(red[0], red[1]), fmaxf(red[2], red[3]));
  xmax = fmaxf(xmax, 1e-5f);
  const float scale = 127.0f / xmax;
  int* qr = (int*)(q + (size_t)row * KDIM);
  qr[threadIdx.x] = pack4q(v0, scale);
  qr[256 + threadIdx.x] = pack4q(v1, scale);
  if (threadIdx.x == 0) rscale[row] = xmax * (1.0f / 127.0f);
}

__global__ __launch_bounds__(256) void quant_w(const float* __restrict__ W,
                                               signed char* __restrict__ Wq) {
  const int i = blockIdx.x * 256 + threadIdx.x;
  float4 v = ((const float4*)W)[i];
  int a = (int)v.x, b = (int)v.y, c = (int)v.z, d = (int)v.w;
  ((int*)Wq)[i] = (a & 0xff) | ((b & 0xff) << 8) | ((c & 0xff) << 16) | ((d & 0xff) << 24);
}

// ---------------- 256x256 8-wave i8 GEMM, 4-deep LDS ring, counted vmcnt ----------------
// K-tile = 64 bytes of K. 32 K-tiles. LDS ring of 4 tile-buffers (A 16KB + B 16KB each).
// Stage S(t) = 4 global_load_lds calls (per-wave vmcnt +4), issued during tile t-3.
// Boundary wait W(t): vmcnt(8) (leave S(t+1),S(t+2) in flight), then s_barrier.
// LDS swizzle: slot ^= (row & 3)  (16B slots, 64B rows) — applied on global source
// (linear global_load_lds dest) and on ds_read addresses.

#define VM8 asm volatile("s_waitcnt vmcnt(8)" ::: "memory")
#define VM4 asm volatile("s_waitcnt vmcnt(4)" ::: "memory")
#define VM0 asm volatile("s_waitcnt vmcnt(0)" ::: "memory")
#define VMNONE

#define STAGE_A(U, T)                                                        \
  GLOAD16(sa + (T) * 64, lds + (U) * 32768 + dstw);                          \
  GLOAD16(sa + (T) * 64 + 128 * KDIM, lds + (U) * 32768 + 8192 + dstw);
#define STAGE_B(U, T)                                                        \
  GLOAD16(sb + (T) * 64, lds + (U) * 32768 + 16384 + dstw);                  \
  GLOAD16(sb + (T) * 64 + 128 * KDIM, lds + (U) * 32768 + 24576 + dstw);

#define MF(m, n, a) acc[m][n] = __builtin_amdgcn_mfma_i32_16x16x64_i8((a), bf[n], acc[m][n], 0, 0, 0);

#define KTILE(U, T, DOSTAGE, VMEND)                                          \
  {                                                                          \
    /* ---- phase A: read m0-3 + all B, stage A-halves of S(T+3) ---- */     \
    v4i a0 = *(const v4i*)(lds + (U) * 32768 + aRd);                         \
    v4i a1 = *(const v4i*)(lds + (U) * 32768 + aRd + 1024);                  \
    v4i a2 = *(const v4i*)(lds + (U) * 32768 + aRd + 2048);                  \
    v4i a3 = *(const v4i*)(lds + (U) * 32768 + aRd + 3072);                  \
    bf[0] = *(const v4i*)(lds + (U) * 32768 + bRd);                          \
    bf[1] = *(const v4i*)(lds + (U) * 32768 + bRd + 1024);                   \
    bf[2] = *(const v4i*)(lds + (U) * 32768 + bRd + 2048);                   \
    bf[3] = *(const v4i*)(lds + (U) * 32768 + bRd + 3072);                   \
    if (DOSTAGE) { STAGE_A((((U) + 3) & 3), (T) + 3) }                       \
    __builtin_amdgcn_sched_barrier(0);                                       \
    __builtin_amdgcn_s_barrier();                                            \
    asm volatile("s_waitcnt lgkmcnt(0)" ::: "memory");                       \
    __builtin_amdgcn_sched_barrier(0);                                       \
    __builtin_amdgcn_s_setprio(1);                                           \
    MF(0, 0, a0) MF(0, 1, a0) MF(0, 2, a0) MF(0, 3, a0)                      \
    MF(1, 0, a1) MF(1, 1, a1) MF(1, 2, a1) MF(1, 3, a1)                      \
    MF(2, 0, a2) MF(2, 1, a2) MF(2, 2, a2) MF(2, 3, a2)                      \
    MF(3, 0, a3) MF(3, 1, a3) MF(3, 2, a3) MF(3, 3, a3)                      \
    __builtin_amdgcn_s_setprio(0);                                           \
    __builtin_amdgcn_sched_barrier(0);                                       \
    __builtin_amdgcn_s_barrier();                                            \
    /* ---- phase B: read m4-7 (B reused in regs), stage B-halves ---- */    \
    v4i a4 = *(const v4i*)(lds + (U) * 32768 + aRd + 4096);                  \
    v4i a5 = *(const v4i*)(lds + (U) * 32768 + aRd + 5120);                  \
    v4i a6 = *(const v4i*)(lds + (U) * 32768 + aRd + 6144);                  \
    v4i a7 = *(const v4i*)(lds + (U) * 32768 + aRd + 7168);                  \
    if (DOSTAGE) { STAGE_B((((U) + 3) & 3), (T) + 3) }                       \
    __builtin_amdgcn_sched_barrier(0);                                       \
    __builtin_amdgcn_s_barrier();                                            \
    asm volatile("s_waitcnt lgkmcnt(0)" ::: "memory");                       \
    __builtin_amdgcn_sched_barrier(0);                                       \
    __builtin_amdgcn_s_setprio(1);                                           \
    MF(4, 0, a4) MF(4, 1, a4) MF(4, 2, a4) MF(4, 3, a4)                      \
    MF(5, 0, a5) MF(5, 1, a5) MF(5, 2, a5) MF(5, 3, a5)                      \
    MF(6, 0, a6) MF(6, 1, a6) MF(6, 2, a6) MF(6, 3, a6)                      \
    MF(7, 0, a7) MF(7, 1, a7) MF(7, 2, a7) MF(7, 3, a7)                      \
    __builtin_amdgcn_s_setprio(0);                                           \
    __builtin_amdgcn_sched_barrier(0);                                       \
    VMEND;                                                                   \
    __builtin_amdgcn_s_barrier();                                            \
  }

__global__ __launch_bounds__(512, 2) void gemm_i8(const signed char* __restrict__ A,
                                                  const signed char* __restrict__ B,
                                                  const float* __restrict__ rscale,
                                                  float* __restrict__ C) {
  __shared__ __align__(16) signed char lds[131072];
  const int bid = blockIdx.x;
  const int lid = (bid & 7) * 128 + (bid >> 3);  // bijective XCD swizzle (1024 % 8 == 0)
  const int bm = lid >> 3;                       // 128 row tiles
  const int bn = lid & 7;                        // 8 col tiles
  const int tid = threadIdx.x;
  const int wid = tid >> 6;
  const int lane = tid & 63;
  const int wr = wid >> 2, wc = wid & 3;

  // staging: per call, thread covers row = c*128 + wid*16 + (lane>>2), dest slot = lane&3.
  // inverse-swizzled global source slot = (lane&3) ^ (row&3) = (lane&3) ^ ((lane>>2)&3).
  const int srow = wid * 16 + (lane >> 2);
  const int scol = (((lane & 3) ^ ((lane >> 2) & 3)) << 4);
  const signed char* sa = A + (size_t)(bm * 256 + srow) * KDIM + scol;
  const signed char* sb = B + (size_t)(bn * 256 + srow) * KDIM + scol;
  const int dstw = wid << 10;  // wave-uniform LDS chunk; HW adds lane*16

  // ds_read: logical k-slot = lane>>4, row&3 = lane&3 -> swizzled slot
  const int rslot = (((lane >> 4) ^ (lane & 3)) << 4);
  const int aRd = (wr * 128 + (lane & 15)) * 64 + rslot;
  const int bRd = 16384 + (wc * 64 + (lane & 15)) * 64 + rslot;

  v4i acc[8][4] = {};
  v4i bf[4];

  // prologue: stage S(0), S(1), S(2); W(0)
  STAGE_A(0, 0) STAGE_B(0, 0)
  STAGE_A(1, 1) STAGE_B(1, 1)
  STAGE_A(2, 2) STAGE_B(2, 2)
  VM8;
  __builtin_amdgcn_s_barrier();

  for (int ti = 0; ti < 7; ++ti) {
    const int t = ti * 4;
    KTILE(0, t + 0, 1, VM8)
    KTILE(1, t + 1, 1, VM8)
    KTILE(2, t + 2, 1, VM8)
    KTILE(3, t + 3, 1, VM8)
  }
  KTILE(0, 28, 1, VM8)    // stages S(31)
  KTILE(1, 29, 0, VM4)    // W(30)
  KTILE(2, 30, 0, VM0)    // W(31)
  KTILE(3, 31, 0, VMNONE)

  // epilogue: C/D layout col = lane&15, row = (lane>>4)*4 + reg
  const int col0 = bn * 256 + wc * 64 + (lane & 15);
  const int rbase = bm * 256 + wr * 128 + ((lane >> 4) << 2);
  #pragma unroll
  for (int m = 0; m < 8; ++m) {
    #pragma unroll
    for (int r = 0; r < 4; ++r) {
      const int row = rbase + m * 16 + r;
      const float s = rscale[row];
      float* crow = C + (size_t)row * NDIM + col0;
      #pragma unroll
      for (int n = 0; n < 4; ++n) crow[n * 16] = (float)acc[m][n][r] * s;
    }
  }
}

extern "C" void kernel_launch(void* const* d_in, const int* in_sizes, int n_in,
                              void* d_out, int out_size, void* d_ws, size_t ws_size,
                              hipStream_t stream) {
  const float* x = (const float*)d_in[0];
  const float* W = (const float*)d_in[1];
  float* out = (float*)d_out;
  const int M = in_sizes[0] / KDIM;  // 32768

  signed char* q = (signed char*)d_ws;                       // M*K   = 64 MB
  signed char* Wq = q + (size_t)M * KDIM;                    // N*K   =  4 MB
  float* rscale = (float*)(Wq + (size_t)NDIM * KDIM);        // M*4   = 128 KB

  quant_rows<<<M, 256, 0, stream>>>(x, q, rscale);
  quant_w<<<(NDIM * KDIM / 4) / 256, 256, 0, stream>>>(W, Wq);
  gemm_i8<<<(M / 256) * (NDIM / 256), 512, 0, stream>>>(q, Wq, rscale, out);
}

// Round 4
// 233.546 us; speedup vs baseline: 1.1904x; 1.0258x over previous
//
#include <hip/hip_runtime.h>

typedef int v4i __attribute__((ext_vector_type(4)));

#define KDIM 2048
#define NDIM 2048

#define GLOAD16(g, l) __builtin_amdgcn_global_load_lds(                      \
    (const __attribute__((address_space(1))) void*)(g),                      \
    (__attribute__((address_space(3))) void*)(l), 16, 0, 0)

// ---------------- quant kernels ----------------

__device__ __forceinline__ int pack4q(float4 v, float s) {
  int a = __float2int_rn(v.x * s);
  int b = __float2int_rn(v.y * s);
  int c = __float2int_rn(v.z * s);
  int d = __float2int_rn(v.w * s);
  a = max(-128, min(127, a)); b = max(-128, min(127, b));
  c = max(-128, min(127, c)); d = max(-128, min(127, d));
  return (a & 0xff) | ((b & 0xff) << 8) | ((c & 0xff) << 16) | ((d & 0xff) << 24);
}

__global__ __launch_bounds__(256) void quant_rows(const float* __restrict__ x,
                                                  signed char* __restrict__ q,
                                                  float* __restrict__ rscale) {
  const int row = blockIdx.x;
  const float4* xr = (const float4*)(x + (size_t)row * KDIM);
  float4 v0 = xr[threadIdx.x];
  float4 v1 = xr[256 + threadIdx.x];
  float m = fmaxf(fmaxf(fabsf(v0.x), fabsf(v0.y)), fmaxf(fabsf(v0.z), fabsf(v0.w)));
  m = fmaxf(m, fmaxf(fmaxf(fabsf(v1.x), fabsf(v1.y)), fmaxf(fabsf(v1.z), fabsf(v1.w))));
  #pragma unroll
  for (int off = 32; off > 0; off >>= 1) m = fmaxf(m, __shfl_xor(m, off));
  __shared__ float red[4];
  if ((threadIdx.x & 63) == 0) red[threadIdx.x >> 6] = m;
  __syncthreads();
  float xmax = fmaxf(fmaxf(red[0], red[1]), fmaxf(red[2], red[3]));
  xmax = fmaxf(xmax, 1e-5f);
  const float scale = 127.0f / xmax;
  int* qr = (int*)(q + (size_t)row * KDIM);
  qr[threadIdx.x] = pack4q(v0, scale);
  qr[256 + threadIdx.x] = pack4q(v1, scale);
  if (threadIdx.x == 0) rscale[row] = xmax * (1.0f / 127.0f);
}

__global__ __launch_bounds__(256) void quant_w(const float* __restrict__ W,
                                               signed char* __restrict__ Wq) {
  const int i = blockIdx.x * 256 + threadIdx.x;
  float4 v = ((const float4*)W)[i];
  int a = (int)v.x, b = (int)v.y, c = (int)v.z, d = (int)v.w;
  ((int*)Wq)[i] = (a & 0xff) | ((b & 0xff) << 8) | ((c & 0xff) << 16) | ((d & 0xff) << 24);
}

// ---------------- 256x256 8-wave i8 GEMM, 4-deep LDS ring, counted vmcnt ----------------
// K-tile = 64 bytes of K. 32 K-tiles. LDS ring of 4 tile-buffers (A 16KB + B 16KB each).
// Stage S(t) = 4 global_load_lds calls (per-wave vmcnt +4), issued during tile t-3.
// Boundary wait W(t): vmcnt(8) (leave S(t+1),S(t+2) in flight), then s_barrier.
// LDS swizzle: physical 16B slot = logical slot ^ ((row>>1)&3).
//   Rationale: rows are 64 B, bank period is 128 B; XOR over (row>>1)&3 places a
//   quarter-wave's 16 lanes on all 8 period-slots 2-way (2-way is free). XOR over
//   row&3 (round 1) only hit 4 of 8 -> 4-way conflict.
// Applied on the global SOURCE (global_load_lds dest is linear) and on ds_read addrs.

#define VM8 asm volatile("s_waitcnt vmcnt(8)" ::: "memory")
#define VM4 asm volatile("s_waitcnt vmcnt(4)" ::: "memory")
#define VM0 asm volatile("s_waitcnt vmcnt(0)" ::: "memory")
#define VMNONE

#define STAGE_A(U, T)                                                        \
  GLOAD16(sa + (T) * 64, lds + (U) * 32768 + dstw);                          \
  GLOAD16(sa + (T) * 64 + 128 * KDIM, lds + (U) * 32768 + 8192 + dstw);
#define STAGE_B(U, T)                                                        \
  GLOAD16(sb + (T) * 64, lds + (U) * 32768 + 16384 + dstw);                  \
  GLOAD16(sb + (T) * 64 + 128 * KDIM, lds + (U) * 32768 + 24576 + dstw);

#define MF(m, n, a) acc[m][n] = __builtin_amdgcn_mfma_i32_16x16x64_i8((a), bf[n], acc[m][n], 0, 0, 0);

#define KTILE(U, T, DOSTAGE, VMEND)                                          \
  {                                                                          \
    /* ---- phase A: read m0-3 + all B, stage A-halves of S(T+3) ---- */     \
    v4i a0 = *(const v4i*)(lds + (U) * 32768 + aRd);                         \
    v4i a1 = *(const v4i*)(lds + (U) * 32768 + aRd + 1024);                  \
    v4i a2 = *(const v4i*)(lds + (U) * 32768 + aRd + 2048);                  \
    v4i a3 = *(const v4i*)(lds + (U) * 32768 + aRd + 3072);                  \
    bf[0] = *(const v4i*)(lds + (U) * 32768 + bRd);                          \
    bf[1] = *(const v4i*)(lds + (U) * 32768 + bRd + 1024);                   \
    bf[2] = *(const v4i*)(lds + (U) * 32768 + bRd + 2048);                   \
    bf[3] = *(const v4i*)(lds + (U) * 32768 + bRd + 3072);                   \
    if (DOSTAGE) { STAGE_A((((U) + 3) & 3), (T) + 3) }                       \
    __builtin_amdgcn_sched_barrier(0);                                       \
    __builtin_amdgcn_s_barrier();                                            \
    asm volatile("s_waitcnt lgkmcnt(0)" ::: "memory");                       \
    __builtin_amdgcn_sched_barrier(0);                                       \
    __builtin_amdgcn_s_setprio(1);                                           \
    MF(0, 0, a0) MF(0, 1, a0) MF(0, 2, a0) MF(0, 3, a0)                      \
    MF(1, 0, a1) MF(1, 1, a1) MF(1, 2, a1) MF(1, 3, a1)                      \
    MF(2, 0, a2) MF(2, 1, a2) MF(2, 2, a2) MF(2, 3, a2)                      \
    MF(3, 0, a3) MF(3, 1, a3) MF(3, 2, a3) MF(3, 3, a3)                      \
    __builtin_amdgcn_s_setprio(0);                                           \
    __builtin_amdgcn_sched_barrier(0);                                       \
    __builtin_amdgcn_s_barrier();                                            \
    /* ---- phase B: read m4-7 (B reused in regs), stage B-halves ---- */    \
    v4i a4 = *(const v4i*)(lds + (U) * 32768 + aRd + 4096);                  \
    v4i a5 = *(const v4i*)(lds + (U) * 32768 + aRd + 5120);                  \
    v4i a6 = *(const v4i*)(lds + (U) * 32768 + aRd + 6144);                  \
    v4i a7 = *(const v4i*)(lds + (U) * 32768 + aRd + 7168);                  \
    if (DOSTAGE) { STAGE_B((((U) + 3) & 3), (T) + 3) }                       \
    __builtin_amdgcn_sched_barrier(0);                                       \
    __builtin_amdgcn_s_barrier();                                            \
    asm volatile("s_waitcnt lgkmcnt(0)" ::: "memory");                       \
    __builtin_amdgcn_sched_barrier(0);                                       \
    __builtin_amdgcn_s_setprio(1);                                           \
    MF(4, 0, a4) MF(4, 1, a4) MF(4, 2, a4) MF(4, 3, a4)                      \
    MF(5, 0, a5) MF(5, 1, a5) MF(5, 2, a5) MF(5, 3, a5)                      \
    MF(6, 0, a6) MF(6, 1, a6) MF(6, 2, a6) MF(6, 3, a6)                      \
    MF(7, 0, a7) MF(7, 1, a7) MF(7, 2, a7) MF(7, 3, a7)                      \
    __builtin_amdgcn_s_setprio(0);                                           \
    __builtin_amdgcn_sched_barrier(0);                                       \
    VMEND;                                                                   \
    __builtin_amdgcn_s_barrier();                                            \
  }

__global__ __launch_bounds__(512, 2) void gemm_i8(const signed char* __restrict__ A,
                                                  const signed char* __restrict__ B,
                                                  const float* __restrict__ rscale,
                                                  float* __restrict__ C) {
  __shared__ __align__(16) signed char lds[131072];
  const int bid = blockIdx.x;
  const int lid = (bid & 7) * 128 + (bid >> 3);  // bijective XCD swizzle (1024 % 8 == 0)
  const int bm = lid >> 3;                       // 128 row tiles
  const int bn = lid & 7;                        // 8 col tiles
  const int tid = threadIdx.x;
  const int wid = tid >> 6;
  const int lane = tid & 63;
  const int wr = wid >> 2, wc = wid & 3;

  // staging: per call, thread covers row = wid*16 + (lane>>2) (within a 128-row half),
  // physical dest slot = lane&3 (HW linear: base + lane*16).
  // source logical slot = (lane&3) ^ ((row>>1)&3) = (lane&3) ^ ((lane>>3)&3).
  const int srow = wid * 16 + (lane >> 2);
  const int scol = (((lane & 3) ^ ((lane >> 3) & 3)) << 4);
  const signed char* sa = A + (size_t)(bm * 256 + srow) * KDIM + scol;
  const signed char* sb = B + (size_t)(bn * 256 + srow) * KDIM + scol;
  const int dstw = wid << 10;  // wave-uniform LDS chunk; HW adds lane*16

  // ds_read: logical k-slot = lane>>4, row = ...+(lane&15) (upper row bits ≡0 mod 4
  // after >>1), so physical slot = (lane>>4) ^ ((lane>>1)&3).
  const int rslot = (((lane >> 4) ^ ((lane >> 1) & 3)) << 4);
  const int aRd = (wr * 128 + (lane & 15)) * 64 + rslot;
  const int bRd = 16384 + (wc * 64 + (lane & 15)) * 64 + rslot;

  v4i acc[8][4] = {};
  v4i bf[4];

  // prologue: stage S(0), S(1), S(2); W(0)
  STAGE_A(0, 0) STAGE_B(0, 0)
  STAGE_A(1, 1) STAGE_B(1, 1)
  STAGE_A(2, 2) STAGE_B(2, 2)
  VM8;
  __builtin_amdgcn_s_barrier();

  for (int ti = 0; ti < 7; ++ti) {
    const int t = ti * 4;
    KTILE(0, t + 0, 1, VM8)
    KTILE(1, t + 1, 1, VM8)
    KTILE(2, t + 2, 1, VM8)
    KTILE(3, t + 3, 1, VM8)
  }
  KTILE(0, 28, 1, VM8)    // stages S(31)
  KTILE(1, 29, 0, VM4)    // W(30)
  KTILE(2, 30, 0, VM0)    // W(31)
  KTILE(3, 31, 0, VMNONE)

  // epilogue: C/D layout col = lane&15, row = (lane>>4)*4 + reg
  const int col0 = bn * 256 + wc * 64 + (lane & 15);
  const int rbase = bm * 256 + wr * 128 + ((lane >> 4) << 2);
  #pragma unroll
  for (int m = 0; m < 8; ++m) {
    #pragma unroll
    for (int r = 0; r < 4; ++r) {
      const int row = rbase + m * 16 + r;
      const float s = rscale[row];
      float* crow = C + (size_t)row * NDIM + col0;
      #pragma unroll
      for (int n = 0; n < 4; ++n) crow[n * 16] = (float)acc[m][n][r] * s;
    }
  }
}

extern "C" void kernel_launch(void* const* d_in, const int* in_sizes, int n_in,
                              void* d_out, int out_size, void* d_ws, size_t ws_size,
                              hipStream_t stream) {
  const float* x = (const float*)d_in[0];
  const float* W = (const float*)d_in[1];
  float* out = (float*)d_out;
  const int M = in_sizes[0] / KDIM;  // 32768

  signed char* q = (signed char*)d_ws;                       // M*K   = 64 MB
  signed char* Wq = q + (size_t)M * KDIM;                    // N*K   =  4 MB
  float* rscale = (float*)(Wq + (size_t)NDIM * KDIM);        // M*4   = 128 KB

  quant_rows<<<M, 256, 0, stream>>>(x, q, rscale);
  quant_w<<<(NDIM * KDIM / 4) / 256, 256, 0, stream>>>(W, Wq);
  gemm_i8<<<(M / 256) * (NDIM / 256), 512, 0, stream>>>(q, Wq, rscale, out);
}